// Round 3
// baseline (250.458 us; speedup 1.0000x reference)
//
#include <hip/hip_runtime.h>
#include <math.h>

#define NQ    64
#define DIM   256
#define SEQ   128
#define CAP   500000
#define TOPK  5
#define KPT   16                  // keys per tile (per wave)
#define NT2   (CAP / KPT)         // 31250 exact
#define NBLK  768                 // 3 blocks/CU * 256 CU
#define NW    (NBLK * 4)          // 3072 waves
#define PB    8                   // per-block per-query candidates
#define NC    (NBLK * PB)         // 6144 candidates per query
#define DELTA 2.0e-3f             // bf16-sim safety margin (~20 sigma)
#define MAXC  192

typedef short short8v __attribute__((ext_vector_type(8)));
typedef float f32x4   __attribute__((ext_vector_type(4)));

__device__ inline unsigned pkbf(float a, float b) {   // 2x fp32 -> packed bf16 (RNE)
    unsigned ua = __builtin_bit_cast(unsigned, a);
    unsigned ub = __builtin_bit_cast(unsigned, b);
    ua = (ua + 0x7fffu + ((ua >> 16) & 1u)) >> 16;
    ub = (ub + 0x7fffu + ((ub >> 16) & 1u)) >> 16;
    return ua | (ub << 16);
}

// ------- Kernel A1: query partial sums (4 chunks of S) + counts copy --------
__global__ void qmean_part_kernel(const float* __restrict__ query,
                                  const float* __restrict__ ac,
                                  float* __restrict__ qpart,
                                  float* __restrict__ outCnt) {
    int blk = blockIdx.x;          // 256
    int d = threadIdx.x;           // 256
    int b = blk >> 2, ch = blk & 3;
    const float* qb = query + ((size_t)b * SEQ + ch * 32) * DIM;
    float s = 0.f;
    #pragma unroll 4
    for (int t = 0; t < 32; ++t) s += qb[(size_t)t * DIM + d];
    qpart[blk * DIM + d] = s;
    // counts passthrough (d_out poisoned before timing)
    for (int i = blk * 256 + d; i < CAP / 4; i += 256 * 256)
        ((float4*)outCnt)[i] = ((const float4*)ac)[i];
}

// ------- Kernel A2: combine partials, mean, L2 normalize --------------------
__global__ void qmean_norm2_kernel(const float* __restrict__ qpart,
                                   float* __restrict__ qn) {
    int b = blockIdx.x;            // 64
    int d = threadIdx.x;           // 256
    float s = qpart[(b * 4 + 0) * DIM + d] + qpart[(b * 4 + 1) * DIM + d]
            + qpart[(b * 4 + 2) * DIM + d] + qpart[(b * 4 + 3) * DIM + d];
    float m = s * (1.0f / SEQ);
    float ss = m * m;
    #pragma unroll
    for (int off = 32; off > 0; off >>= 1) ss += __shfl_down(ss, off, 64);
    __shared__ float red[4];
    if ((threadIdx.x & 63) == 0) red[threadIdx.x >> 6] = ss;
    __syncthreads();
    float tot = red[0] + red[1] + red[2] + red[3];
    float r = 1.0f / fmaxf(sqrtf(tot), 1e-12f);
    qn[b * DIM + d] = m * r;
}

// ------- Kernel B: barrier-free per-wave bf16-MFMA sims + top-8 -------------
// Each wave grid-strides over 16-key tiles. Keys: global->reg in A-frag layout
// (lane = key row l&15, k-slice (l>>4)*8), rk folded pre-bf16. Queries: one
// shared swizzled bf16 LDS image (B-frags). Sims transposed lane->query via
// wave-private LDS (lgkmcnt sync only). One __syncthreads at final merge.
__global__ __launch_bounds__(256, 3) void sims_mfma_topk(
        const float* __restrict__ keys, const float* __restrict__ qn,
        float* __restrict__ candV, int* __restrict__ candI) {
    __shared__ __align__(16) char qlds[64 * 512];     // 32 KB bf16, XOR-swizzled
    __shared__ __align__(16) char simsbuf[4 * 5120];  // 20 KB: per-wave sims / merge

    const int tid  = threadIdx.x;
    const int lane = tid & 63;
    const int wave = tid >> 6;
    const int row  = lane & 15;    // A key-row / D query-col
    const int g    = lane >> 4;    // k-chunk group

    // ---- fill shared query image: bf16, row q = 512B, byte ^= (q&7)<<4 ----
    {
        int q = tid >> 2, quarter = tid & 3;
        const float* src = qn + q * DIM + quarter * 64;
        char* dst = qlds + q * 512;
        #pragma unroll
        for (int m = 0; m < 8; ++m) {
            float4 a = ((const float4*)src)[2 * m];
            float4 b = ((const float4*)src)[2 * m + 1];
            uint4 w;
            w.x = pkbf(a.x, a.y); w.y = pkbf(a.z, a.w);
            w.z = pkbf(b.x, b.y); w.w = pkbf(b.z, b.w);
            unsigned off = ((unsigned)((quarter * 8 + m) * 16)) ^ ((unsigned)(q & 7) << 4);
            *(uint4*)(dst + off) = w;
        }
    }
    __syncthreads();

    float tv[PB]; int ti[PB];
    #pragma unroll
    for (int p = 0; p < PB; ++p) { tv[p] = -INFINITY; ti[p] = 0; }

    const int wgid = blockIdx.x * 4 + wave;
    float4 stg[16];
    auto issue = [&](int t) {
        const float* base = keys + (size_t)t * KPT * DIM + (size_t)row * DIM + g * 8;
        #pragma unroll
        for (int st = 0; st < 8; ++st) {
            stg[2 * st]     = *(const float4*)(base + st * 32);
            stg[2 * st + 1] = *(const float4*)(base + st * 32 + 4);
        }
    };

    char* swave = simsbuf + wave * 5120;
    int t = wgid;
    issue(t);

    while (t < NT2) {
        const int tn = t + NW;
        // ---- key ssq over lane's g-slice, reduce across 4 groups ----
        float ssq = 0.f;
        #pragma unroll
        for (int j = 0; j < 16; ++j) {
            float4 v = stg[j];
            ssq += v.x * v.x + v.y * v.y + v.z * v.z + v.w * v.w;
        }
        ssq += __shfl_xor(ssq, 16, 64);
        ssq += __shfl_xor(ssq, 32, 64);
        float rk = rsqrtf(fmaxf(ssq, 1e-24f));

        // ---- scale + convert to bf16 A-frags ----
        short8v afr[8];
        #pragma unroll
        for (int st = 0; st < 8; ++st) {
            float4 a = stg[2 * st], b = stg[2 * st + 1];
            uint4 w;
            w.x = pkbf(a.x * rk, a.y * rk); w.y = pkbf(a.z * rk, a.w * rk);
            w.z = pkbf(b.x * rk, b.y * rk); w.w = pkbf(b.z * rk, b.w * rk);
            afr[st] = __builtin_bit_cast(short8v, w);
        }
        if (tn < NT2) issue(tn);   // prefetch next tile under MFMA phase

        // ---- MFMA: A=keys(16) x B=queries(4 subtiles), K=256 ----
        f32x4 acc[4];
        #pragma unroll
        for (int s = 0; s < 4; ++s) acc[s] = (f32x4){0.f, 0.f, 0.f, 0.f};
        #pragma unroll
        for (int st = 0; st < 8; ++st) {
            unsigned koff = ((unsigned)(st * 64 + g * 16)) ^ ((unsigned)(row & 7) << 4);
            #pragma unroll
            for (int s = 0; s < 4; ++s) {
                short8v bq = *(const short8v*)(qlds + (s * 16 + row) * 512 + koff);
                acc[s] = __builtin_amdgcn_mfma_f32_16x16x32_bf16(afr[st], bq, acc[s], 0, 0, 0);
            }
        }

        // ---- within-wave transpose: D(row=key g*4+r, col=query s*16+row) ----
        // sims layout [64 q][20 f] (80 B rows, 16B-aligned, bank-verified free)
        #pragma unroll
        for (int s = 0; s < 4; ++s)
            *(f32x4*)(swave + (s * 16 + row) * 80 + g * 16) = acc[s];
        asm volatile("s_waitcnt lgkmcnt(0)" ::: "memory");
        __builtin_amdgcn_wave_barrier();

        // ---- lane = query: scan 16 keys, top-8 insert ----
        #pragma unroll
        for (int c = 0; c < 4; ++c) {
            f32x4 rv = *(const f32x4*)(swave + lane * 80 + c * 16);
            #pragma unroll
            for (int j = 0; j < 4; ++j) {
                float v = rv[j];
                if (v > tv[PB - 1]) {
                    tv[PB - 1] = v; ti[PB - 1] = t * KPT + c * 4 + j;
                    #pragma unroll
                    for (int p = PB - 1; p > 0; --p) {
                        if (tv[p] > tv[p - 1]) {
                            float fv = tv[p]; tv[p] = tv[p - 1]; tv[p - 1] = fv;
                            int   fi = ti[p]; ti[p] = ti[p - 1]; ti[p - 1] = fi;
                        }
                    }
                }
            }
        }
        t = tn;
    }

    // ---- block merge: 4 wave-lists (disjoint key slices) -> top-8/query ----
    float* mv = (float*)simsbuf;                 // [4][64][8] vals (8 KB)
    int*   mi = (int*)simsbuf + 4 * 64 * 8;      // [4][64][8] idx  (8 KB)
    __syncthreads();                             // sims region now free
    {
        int base = (wave * 64 + lane) * PB;
        #pragma unroll
        for (int p = 0; p < PB; ++p) { mv[base + p] = tv[p]; mi[base + p] = ti[p]; }
    }
    __syncthreads();
    if (wave == 0) {
        float fv[PB]; int fi[PB];
        #pragma unroll
        for (int p = 0; p < PB; ++p) { fv[p] = -INFINITY; fi[p] = 0; }
        for (int w = 0; w < 4; ++w) {
            #pragma unroll
            for (int p = 0; p < PB; ++p) {
                float v = mv[(w * 64 + lane) * PB + p];
                int  id = mi[(w * 64 + lane) * PB + p];
                if (v > fv[PB - 1]) {
                    fv[PB - 1] = v; fi[PB - 1] = id;
                    #pragma unroll
                    for (int p2 = PB - 1; p2 > 0; --p2) {
                        if (fv[p2] > fv[p2 - 1]) {
                            float a = fv[p2]; fv[p2] = fv[p2 - 1]; fv[p2 - 1] = a;
                            int   c = fi[p2]; fi[p2] = fi[p2 - 1]; fi[p2 - 1] = c;
                        }
                    }
                }
            }
        }
        size_t cb = ((size_t)lane * NBLK + blockIdx.x) * PB;
        #pragma unroll
        for (int p = 0; p < PB; ++p) { candV[cb + p] = fv[p]; candI[cb + p] = fi[p]; }
    }
}

// ---- Kernel C: global bf16-top5 -> threshold select -> exact fp32 rescore ----
__global__ void finalize_kernel(const float* __restrict__ candV,
                                const int* __restrict__ candI,
                                const float* __restrict__ keys,
                                const float* __restrict__ qn,
                                const float* __restrict__ values,
                                float* __restrict__ outRet,
                                float* __restrict__ outCnt) {
    const int b = blockIdx.x;      // query
    const int t = threadIdx.x;     // 256
    const int lane = t & 63, wave = t >> 6;
    __shared__ float rv[256]; __shared__ int rp[256];
    __shared__ int   chosen[TOPK];
    __shared__ float v5s;
    __shared__ int   clist[MAXC];
    __shared__ float rsc[MAXC];
    __shared__ int   ccnt;
    __shared__ float qs[DIM];
    __shared__ int   kidx[TOPK];

    const float* cv = candV + (size_t)b * NC;
    const int*   ci = candI + (size_t)b * NC;

    // phase 1: 5 argmax passes over bf16-sims -> v5 (5th largest)
    for (int pass = 0; pass < TOPK; ++pass) {
        float lv = -INFINITY; int lp = 0x7fffffff;
        for (int m = t; m < NC; m += 256) {
            bool skip = false;
            for (int k2 = 0; k2 < pass; ++k2) skip |= (m == chosen[k2]);
            float v = cv[m];
            if (!skip && (v > lv || (v == lv && m < lp))) { lv = v; lp = m; }
        }
        rv[t] = lv; rp[t] = lp;
        __syncthreads();
        for (int s = 128; s > 0; s >>= 1) {
            if (t < s) {
                if (rv[t + s] > rv[t] || (rv[t + s] == rv[t] && rp[t + s] < rp[t])) {
                    rv[t] = rv[t + s]; rp[t] = rp[t + s];
                }
            }
            __syncthreads();
        }
        if (t == 0) { chosen[pass] = rp[0]; if (pass == TOPK - 1) v5s = rv[0]; }
        __syncthreads();
    }

    // phase 2: collect candidates >= v5 - DELTA (provable superset of true top5)
    if (t == 0) ccnt = 0;
    __syncthreads();
    float thr = v5s - DELTA;
    for (int m = t; m < NC; m += 256) {
        if (cv[m] >= thr) {
            int pos = atomicAdd(&ccnt, 1);
            if (pos < MAXC) clist[pos] = ci[m];
        }
    }
    qs[t] = qn[b * DIM + t];
    __syncthreads();
    int cnt = min(ccnt, MAXC);

    // phase 3: exact fp32 rescore (one wave per candidate)
    for (int c = wave; c < cnt; c += 4) {
        const float4 k4 = *(const float4*)(keys + (size_t)clist[c] * DIM + lane * 4);
        const float4 q4 = *(const float4*)(qs + lane * 4);
        float d  = q4.x * k4.x + q4.y * k4.y + q4.z * k4.z + q4.w * k4.w;
        float s2 = k4.x * k4.x + k4.y * k4.y + k4.z * k4.z + k4.w * k4.w;
        #pragma unroll
        for (int off = 1; off < 64; off <<= 1) {
            d  += __shfl_xor(d, off, 64);
            s2 += __shfl_xor(s2, off, 64);
        }
        if (lane == 0) rsc[c] = d * rsqrtf(fmaxf(s2, 1e-24f));
    }
    __syncthreads();

    // phase 4: exact top-5 among rescored candidates
    for (int pass = 0; pass < TOPK; ++pass) {
        float lv = -INFINITY; int lp = 0x7fffffff;
        if (t < cnt) {
            bool skip = false;
            for (int k2 = 0; k2 < pass; ++k2) skip |= (t == chosen[k2]);
            if (!skip) { lv = rsc[t]; lp = t; }
        }
        rv[t] = lv; rp[t] = lp;
        __syncthreads();
        for (int s = 128; s > 0; s >>= 1) {
            if (t < s) {
                if (rv[t + s] > rv[t] || (rv[t + s] == rv[t] && rp[t + s] < rp[t])) {
                    rv[t] = rv[t + s]; rp[t] = rp[t + s];
                }
            }
            __syncthreads();
        }
        if (t == 0) { chosen[pass] = rp[0]; kidx[pass] = clist[rp[0]]; }
        __syncthreads();
    }

    // phase 5: gather values + mean; scatter counts
    float s = 0.f;
    #pragma unroll
    for (int p = 0; p < TOPK; ++p) s += values[(size_t)kidx[p] * DIM + t];
    outRet[b * DIM + t] = s * 0.2f;
    if (t < TOPK) atomicAdd(&outCnt[kidx[t]], 1.0f);
}

// ---------------- launch -----------------------------------------------------
extern "C" void kernel_launch(void* const* d_in, const int* in_sizes, int n_in,
                              void* d_out, int out_size, void* d_ws, size_t ws_size,
                              hipStream_t stream) {
    const float* query  = (const float*)d_in[0];
    const float* keys   = (const float*)d_in[1];
    const float* values = (const float*)d_in[2];
    const float* acnt   = (const float*)d_in[3];
    float* outRet = (float*)d_out;
    float* outCnt = outRet + NQ * DIM;

    char* ws = (char*)d_ws;
    float* qn    = (float*)ws;                                   // 64 KB
    float* qpart = (float*)(ws + 65536);                         // 256 KB
    float* candV = (float*)(ws + 65536 + 262144);                // 1.5 MB
    int*   candI = (int*)(ws + 65536 + 262144 + (size_t)NQ * NC * 4);

    qmean_part_kernel<<<256, 256, 0, stream>>>(query, acnt, qpart, outCnt);
    qmean_norm2_kernel<<<NQ, 256, 0, stream>>>(qpart, qn);
    sims_mfma_topk<<<NBLK, 256, 0, stream>>>(keys, qn, candV, candI);
    finalize_kernel<<<NQ, 256, 0, stream>>>(candV, candI, keys, qn, values,
                                            outRet, outCnt);
}